// Round 6
// baseline (220.212 us; speedup 1.0000x reference)
//
#include <hip/hip_runtime.h>
#include <hip/hip_bf16.h>
#include <cstdint>
#include <cstddef>

// Problem dims (fixed)
#define B_   4
#define N_   1024
#define C_   768
#define H_   12
#define D_   64
#define HID_ 3072
#define M_   4096  // B*N

typedef __attribute__((ext_vector_type(8))) short short8;
typedef __attribute__((ext_vector_type(8))) unsigned short ushort8;
typedef __attribute__((ext_vector_type(4))) float f32x4;

__device__ __forceinline__ void gload16(const void* g, void* l) {
  __builtin_amdgcn_global_load_lds(
      (const __attribute__((address_space(1))) void*)g,
      (__attribute__((address_space(3))) void*)l, 16, 0, 0);
}

__device__ __forceinline__ unsigned short f2bf(float f) {
  __hip_bfloat16 h = __float2bfloat16(f);
  return __builtin_bit_cast(unsigned short, h);
}
__device__ __forceinline__ float bf2f(unsigned short u) {
  unsigned int x = ((unsigned int)u) << 16;
  return __builtin_bit_cast(float, x);
}
__device__ __forceinline__ float ex2(float x) {
  float r;
  asm("v_exp_f32 %0, %1" : "=v"(r) : "v"(x));
  return r;
}
__device__ __forceinline__ float lg2(float x) {
  float r;
  asm("v_log_f32 %0, %1" : "=v"(r) : "v"(x));
  return r;
}
__device__ __forceinline__ float frcp(float x) {
  float r;
  asm("v_rcp_f32 %0, %1" : "=v"(r) : "v"(x));
  return r;
}

// ---------------- merged weight fp32 -> bf16 transpose ----------------
__global__ __launch_bounds__(256) void wconv_all(
    const float* __restrict__ qkv_w, const float* __restrict__ proj_w,
    const float* __restrict__ fc1_w, const float* __restrict__ fc2_w,
    unsigned short* __restrict__ wt_qkv, unsigned short* __restrict__ wt_proj,
    unsigned short* __restrict__ wt_fc1, unsigned short* __restrict__ wt_fc2) {
  __shared__ float tile[32][33];
  const int bid = blockIdx.x;
  const float* W;
  unsigned short* Wt;
  int K, Nn, bx, by;
  if (bid < 1728) {
    W = qkv_w; Wt = wt_qkv; K = 768; Nn = 2304;
    bx = bid % 72; by = bid / 72;
  } else if (bid < 1728 + 576) {
    const int i = bid - 1728;
    W = proj_w; Wt = wt_proj; K = 768; Nn = 768;
    bx = i % 24; by = i / 24;
  } else if (bid < 1728 + 576 + 2304) {
    const int i = bid - (1728 + 576);
    W = fc1_w; Wt = wt_fc1; K = 768; Nn = 3072;
    bx = i % 96; by = i / 96;
  } else {
    const int i = bid - (1728 + 576 + 2304);
    W = fc2_w; Wt = wt_fc2; K = 3072; Nn = 768;
    bx = i % 24; by = i / 24;
  }
  const int tx = threadIdx.x & 31, ty = threadIdx.x >> 5;  // 32 x 8
  const int n0 = bx * 32, k0 = by * 32;
#pragma unroll
  for (int i = 0; i < 32; i += 8)
    tile[ty + i][tx] = W[(size_t)(k0 + ty + i) * Nn + n0 + tx];
  __syncthreads();
#pragma unroll
  for (int i = 0; i < 32; i += 8)
    Wt[(size_t)(n0 + ty + i) * K + k0 + tx] = f2bf(tile[tx][ty + i]);
}

// ---------------- LayerNorm (fp32 in -> bf16 out) ----------------
__global__ __launch_bounds__(256) void ln_kernel(const float* __restrict__ x,
                                                 const float* __restrict__ w,
                                                 const float* __restrict__ b,
                                                 unsigned short* __restrict__ out) {
  __shared__ float sbuf[8];
  const int row = blockIdx.x;
  const int t = threadIdx.x;
  const float* xr = x + (size_t)row * C_;
  float v0 = xr[t], v1 = xr[t + 256], v2 = xr[t + 512];
  float s = v0 + v1 + v2;
  float ss = v0 * v0 + v1 * v1 + v2 * v2;
#pragma unroll
  for (int m = 32; m >= 1; m >>= 1) {
    s += __shfl_xor(s, m);
    ss += __shfl_xor(ss, m);
  }
  const int wave = t >> 6, lane = t & 63;
  if (lane == 0) { sbuf[wave] = s; sbuf[4 + wave] = ss; }
  __syncthreads();
  s = sbuf[0] + sbuf[1] + sbuf[2] + sbuf[3];
  ss = sbuf[4] + sbuf[5] + sbuf[6] + sbuf[7];
  const float mu = s * (1.f / C_);
  const float var = ss * (1.f / C_) - mu * mu;
  const float rstd = rsqrtf(var + 1e-6f);
  unsigned short* o = out + (size_t)row * C_;
  o[t]       = f2bf((v0 - mu) * rstd * w[t]       + b[t]);
  o[t + 256] = f2bf((v1 - mu) * rstd * w[t + 256] + b[t + 256]);
  o[t + 512] = f2bf((v2 - mu) * rstd * w[t + 512] + b[t + 512]);
}

// ---------------- GEMM: C = A[M,K] * Bt[N,K]^T + bias, fused epilogue ----------
// BM = MF*32 (MF=4 -> 128, MF=2 -> 64), BN=128, BK=32, 4 waves.
// Depth-4 prefetch, 5 LDS buffers, counted vmcnt, raw s_barrier, setprio.
// XCD stripe swizzle: xcd owns a contiguous bm stripe (A slice L2-fits).
template <int MF, bool GELU, bool RES, bool OUTF, bool OUTB>
__global__ __launch_bounds__(256) void gemm_bt(const unsigned short* __restrict__ A,
                                               const unsigned short* __restrict__ Bt,
                                               const float* __restrict__ bias,
                                               const float* __restrict__ res,
                                               float* __restrict__ outF,
                                               unsigned short* __restrict__ outB,
                                               int M, int Nn, int K) {
  __shared__ unsigned short As[5][MF * 32 * 32];
  __shared__ unsigned short Bs[5][128 * 32];
  const int t = threadIdx.x;
  const int lane = t & 63;
  const int wave = t >> 6;
  const int wm = wave >> 1, wn = wave & 1;
  const int r15 = lane & 15, g = lane >> 4;

  // XCD stripe swizzle; SPX = bm-values per xcd
  constexpr int SPX = (MF == 4) ? 4 : 8;
  constexpr int LGS = (MF == 4) ? 2 : 3;
  const int orig = blockIdx.y * gridDim.x + blockIdx.x;
  const int xcd = orig & 7;
  const int j = orig >> 3;
  const int bm = xcd * SPX + (j & (SPX - 1));
  const int bn = j >> LGS;

  f32x4 acc[MF][4];
#pragma unroll
  for (int m = 0; m < MF; ++m)
#pragma unroll
    for (int n = 0; n < 4; ++n) acc[m][n] = (f32x4){0.f, 0.f, 0.f, 0.f};

  const unsigned short* ga0 = A + (size_t)(bm * (MF * 32) + (t >> 2)) * K + (t & 3) * 8;
  const unsigned short* gb0 = Bt + (size_t)(bn * 128 + (t >> 2)) * K + (t & 3) * 8;

#define GSTAGE(kt_, buf_)                                                  \
  {                                                                        \
    const unsigned short* ga = ga0 + (kt_)*32;                             \
    const unsigned short* gb = gb0 + (kt_)*32;                             \
    gload16(ga, (char*)As[buf_] + wave * 1024);                            \
    if constexpr (MF == 4)                                                 \
      gload16(ga + (size_t)64 * K, (char*)As[buf_] + wave * 1024 + 4096);  \
    gload16(gb, (char*)Bs[buf_] + wave * 1024);                            \
    gload16(gb + (size_t)64 * K, (char*)Bs[buf_] + wave * 1024 + 4096);    \
  }

  const int nk = K >> 5;  // >= 24 for all our shapes
  GSTAGE(0, 0);
  GSTAGE(1, 1);
  GSTAGE(2, 2);
  GSTAGE(3, 3);

  int rd = 0;
  for (int kt = 0; kt < nk; ++kt) {
    const int rem = nk - kt;
    if (rem >= 4) {
      if constexpr (MF == 4) asm volatile("s_waitcnt vmcnt(12)" ::: "memory");
      else                   asm volatile("s_waitcnt vmcnt(9)" ::: "memory");
    } else if (rem == 3) {
      if constexpr (MF == 4) asm volatile("s_waitcnt vmcnt(8)" ::: "memory");
      else                   asm volatile("s_waitcnt vmcnt(6)" ::: "memory");
    } else if (rem == 2) {
      if constexpr (MF == 4) asm volatile("s_waitcnt vmcnt(4)" ::: "memory");
      else                   asm volatile("s_waitcnt vmcnt(3)" ::: "memory");
    } else {
      asm volatile("s_waitcnt vmcnt(0)" ::: "memory");
    }
    __builtin_amdgcn_s_barrier();

    short8 af[MF], bf[4];
#pragma unroll
    for (int m = 0; m < MF; ++m)
      af[m] = *(const short8*)(As[rd] + (wm * (MF * 16) + m * 16 + r15) * 32 + g * 8);
#pragma unroll
    for (int n = 0; n < 4; ++n)
      bf[n] = *(const short8*)(Bs[rd] + (wn * 64 + n * 16 + r15) * 32 + g * 8);

    if (kt + 4 < nk) {
      const int wr = (rd == 0) ? 4 : rd - 1;  // == (kt+4)%5
      GSTAGE(kt + 4, wr);
    }

    asm volatile("s_waitcnt lgkmcnt(0)" ::: "memory");
    __builtin_amdgcn_sched_barrier(0);
    __builtin_amdgcn_s_setprio(1);
#pragma unroll
    for (int m = 0; m < MF; ++m)
#pragma unroll
      for (int n = 0; n < 4; ++n)
        acc[m][n] = __builtin_amdgcn_mfma_f32_16x16x32_bf16(af[m], bf[n], acc[m][n], 0, 0, 0);
    __builtin_amdgcn_s_setprio(0);
    rd = (rd == 4) ? 0 : rd + 1;
  }
#undef GSTAGE

#pragma unroll
  for (int m = 0; m < MF; ++m) {
#pragma unroll
    for (int n = 0; n < 4; ++n) {
#pragma unroll
      for (int r = 0; r < 4; ++r) {
        const int row = bm * (MF * 32) + wm * (MF * 16) + m * 16 + g * 4 + r;
        const int col = bn * 128 + wn * 64 + n * 16 + r15;
        float v = acc[m][n][r] + bias[col];
        if (GELU) v = 0.5f * v * (1.f + erff(v * 0.70710678118654752f));
        if (RES) v += res[(size_t)row * Nn + col];
        if (OUTF) outF[(size_t)row * Nn + col] = v;
        if (OUTB) outB[(size_t)row * Nn + col] = f2bf(v);
      }
    }
  }
}

// ---------------- fused biased attention, KV-split x2 ----------------
// grid: (N/64, B*H, 2). Split z handles K-tiles [z*8, z*8+8).
// Writes normalized partial On_z (bf16, o-layout) + s_z = m + log2(l) per row.
__global__ __launch_bounds__(256) void attn_kernel(const unsigned short* __restrict__ qkv,
                                                   const float* __restrict__ pbias,
                                                   unsigned short* __restrict__ On0,
                                                   unsigned short* __restrict__ On1,
                                                   float* __restrict__ sbuf) {
  __shared__ unsigned short Ks[2][64 * 64];
  __shared__ unsigned short Vt[64 * 64];
  __shared__ unsigned short Ps[4][16 * 64];
  const int t = threadIdx.x, lane = t & 63, wave = t >> 6;
  const int bh = blockIdx.y;
  const int b = bh / H_, h = bh % H_;
  const int q0 = blockIdx.x * 64;
  const int z = blockIdx.z;
  const int kt0 = z * 8;
  const int r15 = lane & 15, g = lane >> 4;
  const int qrow = q0 + wave * 16;
  const float LOG2E = 1.44269504088896f;
  const float QS = 0.125f * 1.44269504088896f;  // SCALE * log2(e)

  short8 aq[2];
  {
    const unsigned short* qp =
        qkv + (size_t)(b * N_ + qrow + r15) * (3 * C_) + h * D_ + g * 8;
    const ushort8 r0 = *(const ushort8*)qp;
    const ushort8 r1 = *(const ushort8*)(qp + 32);
#pragma unroll
    for (int jj = 0; jj < 8; ++jj) {
      aq[0][jj] = (short)f2bf(bf2f(r0[jj]) * QS);
      aq[1][jj] = (short)f2bf(bf2f(r1[jj]) * QS);
    }
  }

  f32x4 oacc[4];
#pragma unroll
  for (int n = 0; n < 4; ++n) oacc[n] = (f32x4){0.f, 0.f, 0.f, 0.f};
  float m_run[4], l_run[4];
#pragma unroll
  for (int r = 0; r < 4; ++r) { m_run[r] = -1e30f; l_run[r] = 0.f; }

  const unsigned short* kbase = qkv + (size_t)b * N_ * (3 * C_) + C_ + h * D_;
  const unsigned short* vbase = qkv + (size_t)b * N_ * (3 * C_) + 2 * C_ + h * D_;
  const float* bb = pbias + (size_t)b * N_ * N_;

  const int krow = t >> 3;
  const int kchunk = (t & 7) ^ (krow & 7);
  const int vp = t & 31;
  const int vq = t >> 5;
  const int vkey = vp * 2, vd0 = vq * 8;

#define KSTAGE(kt_, nb_)                                                       \
  {                                                                            \
    const unsigned short* kg =                                                 \
        kbase + (size_t)((kt_)*64 + krow) * (3 * C_) + kchunk * 8;             \
    gload16(kg, (char*)Ks[nb_] + wave * 1024);                                 \
    gload16(kg + (size_t)32 * (3 * C_), (char*)Ks[nb_] + wave * 1024 + 4096);  \
  }

#define VWRITE(va_, vb_)                                                             \
  {                                                                                  \
    char* vdst = (char*)Vt;                                                          \
    _Pragma("unroll") for (int jj = 0; jj < 8; ++jj) {                               \
      const int d = vd0 + jj;                                                        \
      const unsigned int pack =                                                      \
          (unsigned int)(va_)[jj] | ((unsigned int)(vb_)[jj] << 16);                 \
      *(unsigned int*)(vdst + d * 128 + (((vp >> 2) ^ (d & 7)) << 4) +               \
                       (vp & 3) * 4) = pack;                                         \
    }                                                                                \
  }

  // Prologue
  KSTAGE(kt0, 0);
  ushort8 va, vb2;
  {
    const unsigned short* vg = vbase + (size_t)(kt0 * 64 + vkey) * (3 * C_) + vd0;
    va = *(const ushort8*)vg;
    vb2 = *(const ushort8*)(vg + 3 * C_);
  }
  float bcur[4][4], bnext[4][4];
#pragma unroll
  for (int n = 0; n < 4; ++n)
#pragma unroll
    for (int r = 0; r < 4; ++r)
      bcur[n][r] = bb[(size_t)(qrow + g * 4 + r) * N_ + kt0 * 64 + n * 16 + r15];

  for (int kb = 0; kb < 8; ++kb) {
    const int kt = kt0 + kb;
    const int cur = kb & 1;
    __syncthreads();  // K[kt] staged & visible; all waves' PV[kb-1] done

    VWRITE(va, vb2);

    const bool more = (kb + 1 < 8);
    if (more) {
      KSTAGE(kt + 1, cur ^ 1);
      const unsigned short* vg =
          vbase + (size_t)((kt + 1) * 64 + vkey) * (3 * C_) + vd0;
      va = *(const ushort8*)vg;
      vb2 = *(const ushort8*)(vg + 3 * C_);
#pragma unroll
      for (int n = 0; n < 4; ++n)
#pragma unroll
        for (int r = 0; r < 4; ++r)
          bnext[n][r] =
              bb[(size_t)(qrow + g * 4 + r) * N_ + (kt + 1) * 64 + n * 16 + r15];
    }

    const unsigned short* Ksc = Ks[cur];
    f32x4 sacc[4];
#pragma unroll
    for (int n = 0; n < 4; ++n) sacc[n] = (f32x4){0.f, 0.f, 0.f, 0.f};
    __builtin_amdgcn_s_setprio(1);
#pragma unroll
    for (int kk = 0; kk < 2; ++kk) {
#pragma unroll
      for (int n = 0; n < 4; ++n) {
        short8 bk = *(const short8*)(Ksc + (n * 16 + r15) * 64 +
                                     (((kk * 4 + g) ^ (r15 & 7)) << 3));
        sacc[n] = __builtin_amdgcn_mfma_f32_16x16x32_bf16(aq[kk], bk, sacc[n], 0, 0, 0);
      }
    }
    __builtin_amdgcn_s_setprio(0);

    float p[4][4], tm[4];
#pragma unroll
    for (int r = 0; r < 4; ++r) tm[r] = -3e38f;
#pragma unroll
    for (int n = 0; n < 4; ++n)
#pragma unroll
      for (int r = 0; r < 4; ++r) {
        const float s = fmaf(bcur[n][r], LOG2E, sacc[n][r]);
        p[n][r] = s;
        tm[r] = fmaxf(tm[r], s);
      }
#pragma unroll
    for (int r = 0; r < 4; ++r) {
      tm[r] = fmaxf(tm[r], __shfl_xor(tm[r], 1));
      tm[r] = fmaxf(tm[r], __shfl_xor(tm[r], 2));
      tm[r] = fmaxf(tm[r], __shfl_xor(tm[r], 4));
      tm[r] = fmaxf(tm[r], __shfl_xor(tm[r], 8));
    }
    int need = 0;
#pragma unroll
    for (int r = 0; r < 4; ++r) need |= (tm[r] > m_run[r] + 8.0f);
    if (__any(need)) {
#pragma unroll
      for (int r = 0; r < 4; ++r) {
        const float mn = fmaxf(m_run[r], tm[r]);
        const float corr = ex2(m_run[r] - mn);
        m_run[r] = mn;
        l_run[r] *= corr;
#pragma unroll
        for (int n = 0; n < 4; ++n) oacc[n][r] *= corr;
      }
    }
    float rs[4] = {0.f, 0.f, 0.f, 0.f};
#pragma unroll
    for (int n = 0; n < 4; ++n)
#pragma unroll
      for (int r = 0; r < 4; ++r) {
        p[n][r] = ex2(p[n][r] - m_run[r]);
        rs[r] += p[n][r];
      }
#pragma unroll
    for (int r = 0; r < 4; ++r) {
      rs[r] += __shfl_xor(rs[r], 1);
      rs[r] += __shfl_xor(rs[r], 2);
      rs[r] += __shfl_xor(rs[r], 4);
      rs[r] += __shfl_xor(rs[r], 8);
      l_run[r] += rs[r];
    }

    unsigned short* Psw = Ps[wave];
#pragma unroll
    for (int n = 0; n < 4; ++n)
#pragma unroll
      for (int r = 0; r < 4; ++r) {
        const int row = g * 4 + r, col = n * 16 + r15;
        Psw[row * 64 + (((col >> 3) ^ (row & 7)) << 3) + (col & 7)] = f2bf(p[n][r]);
      }

    // lgkm-only barrier (global prefetch stays in flight)
    asm volatile("s_waitcnt lgkmcnt(0)" ::: "memory");
    __builtin_amdgcn_s_barrier();
    __builtin_amdgcn_sched_barrier(0);

    __builtin_amdgcn_s_setprio(1);
#pragma unroll
    for (int kk = 0; kk < 2; ++kk) {
      short8 ap = *(const short8*)(Psw + r15 * 64 + (((kk * 4 + g) ^ (r15 & 7)) << 3));
#pragma unroll
      for (int n = 0; n < 4; ++n) {
        short8 bv = *(const short8*)(Vt + (n * 16 + r15) * 64 +
                                     (((kk * 4 + g) ^ (r15 & 7)) << 3));
        oacc[n] = __builtin_amdgcn_mfma_f32_16x16x32_bf16(ap, bv, oacc[n], 0, 0, 0);
      }
    }
    __builtin_amdgcn_s_setprio(0);

    if (more) {
#pragma unroll
      for (int n = 0; n < 4; ++n)
#pragma unroll
        for (int r = 0; r < 4; ++r) bcur[n][r] = bnext[n][r];
    }
  }
#undef KSTAGE
#undef VWRITE

  // write normalized partial + log2-mass
  unsigned short* On = z ? On1 : On0;
  float rl[4];
#pragma unroll
  for (int r = 0; r < 4; ++r) rl[r] = frcp(l_run[r]);
#pragma unroll
  for (int n = 0; n < 4; ++n) {
#pragma unroll
    for (int r = 0; r < 4; ++r) {
      const int row = qrow + g * 4 + r;
      const float v = oacc[n][r] * rl[r];
      On[(size_t)(b * N_ + row) * C_ + h * D_ + n * 16 + r15] = f2bf(v);
    }
  }
  if (r15 == 0) {
#pragma unroll
    for (int r = 0; r < 4; ++r) {
      const int row = qrow + g * 4 + r;
      sbuf[((size_t)(z * B_ + b) * H_ + h) * N_ + row] = m_run[r] + lg2(l_run[r]);
    }
  }
}

// ---------------- attention split-combine ----------------
// o = (w0*On0 + w1*On1) / (w0+w1), w_z = 2^(s_z - max)
__global__ __launch_bounds__(256) void attn_combine(
    const unsigned short* __restrict__ On0, const unsigned short* __restrict__ On1,
    const float* __restrict__ sbuf, unsigned short* __restrict__ o) {
  const int tid = blockIdx.x * 256 + threadIdx.x;
  const size_t base = (size_t)tid * 8;
  const int row = (int)(base / C_);
  const int c = (int)(base % C_);
  const int b = row >> 10;
  const int h = c >> 6;
  const size_t sidx = ((size_t)(b * H_ + h)) * N_ + (row & 1023);
  const float s0 = sbuf[sidx];
  const float s1 = sbuf[(size_t)B_ * H_ * N_ + sidx];
  const float smax = fmaxf(s0, s1);
  const float w0 = ex2(s0 - smax), w1 = ex2(s1 - smax);
  const float inv = frcp(w0 + w1);
  const ushort8 a0 = *(const ushort8*)(On0 + base);
  const ushort8 a1 = *(const ushort8*)(On1 + base);
  ushort8 r;
#pragma unroll
  for (int jj = 0; jj < 8; ++jj)
    r[jj] = f2bf((w0 * bf2f(a0[jj]) + w1 * bf2f(a1[jj])) * inv);
  *(ushort8*)(o + base) = r;
}

// ---------------- launcher ----------------
extern "C" void kernel_launch(void* const* d_in, const int* in_sizes, int n_in,
                              void* d_out, int out_size, void* d_ws, size_t ws_size,
                              hipStream_t stream) {
  const float* x      = (const float*)d_in[0];
  const float* pbias  = (const float*)d_in[1];
  const float* qkv_w  = (const float*)d_in[2];
  const float* qkv_b  = (const float*)d_in[3];
  const float* proj_w = (const float*)d_in[4];
  const float* proj_b = (const float*)d_in[5];
  const float* n1_w   = (const float*)d_in[6];
  const float* n1_b   = (const float*)d_in[7];
  const float* n2_w   = (const float*)d_in[8];
  const float* n2_b   = (const float*)d_in[9];
  const float* fc1_w  = (const float*)d_in[10];
  const float* fc1_b  = (const float*)d_in[11];
  const float* fc2_w  = (const float*)d_in[12];
  const float* fc2_b  = (const float*)d_in[13];
  float* out = (float*)d_out;

  char* ws = (char*)d_ws;
  unsigned short* wt_qkv  = (unsigned short*)(ws + 0);          // 2304x768 bf16
  unsigned short* wt_proj = (unsigned short*)(ws + 3538944);    // 768x768
  unsigned short* wt_fc1  = (unsigned short*)(ws + 4718592);    // 3072x768
  unsigned short* wt_fc2  = (unsigned short*)(ws + 9437184);    // 768x3072
  float*          x2      = (float*)(ws + 14155776);            // 4096x768 fp32
  unsigned short* On1     = (unsigned short*)(ws + 14155776);   // aliases x2 (dead then)
  unsigned short* h1      = (unsigned short*)(ws + 26738688);   // 4096x768 bf16
  unsigned short* qkvb    = (unsigned short*)(ws + 33030144);   // 4096x2304 bf16
  unsigned short* On0     = (unsigned short*)(ws + 51904512);   // 4096x768 bf16
  float*          sb      = (float*)(ws + 58195968);            // [2][4][12][1024] f32

  wconv_all<<<1728 + 576 + 2304 + 2304, 256, 0, stream>>>(
      qkv_w, proj_w, fc1_w, fc2_w, wt_qkv, wt_proj, wt_fc1, wt_fc2);

  ln_kernel<<<M_, 256, 0, stream>>>(x, n1_w, n1_b, h1);
  gemm_bt<4, false, false, false, true><<<dim3(32, 18), 256, 0, stream>>>(
      h1, wt_qkv, qkv_b, nullptr, nullptr, qkvb, M_, 3 * C_, C_);
  attn_kernel<<<dim3(N_ / 64, B_ * H_, 2), 256, 0, stream>>>(qkvb, pbias, On0, On1, sb);
  attn_combine<<<(M_ * C_) / (256 * 8), 256, 0, stream>>>(On0, On1, sb, h1);
  gemm_bt<2, false, true, true, false><<<dim3(64, 6), 256, 0, stream>>>(
      h1, wt_proj, proj_b, x, x2, nullptr, M_, C_, C_);
  ln_kernel<<<M_, 256, 0, stream>>>(x2, n2_w, n2_b, h1);
  gemm_bt<4, true, false, false, true><<<dim3(32, 24), 256, 0, stream>>>(
      h1, wt_fc1, fc1_b, nullptr, nullptr, qkvb, M_, HID_, C_);
  gemm_bt<2, false, true, true, false><<<dim3(64, 6), 256, 0, stream>>>(
      qkvb, wt_fc2, fc2_b, x2, out, nullptr, M_, C_, HID_);
}

// Round 7
// 199.050 us; speedup vs baseline: 1.1063x; 1.1063x over previous
//
#include <hip/hip_runtime.h>
#include <hip/hip_bf16.h>
#include <cstdint>
#include <cstddef>

// Problem dims (fixed)
#define B_   4
#define N_   1024
#define C_   768
#define H_   12
#define D_   64
#define HID_ 3072
#define M_   4096  // B*N

typedef __attribute__((ext_vector_type(8))) short short8;
typedef __attribute__((ext_vector_type(8))) unsigned short ushort8;
typedef __attribute__((ext_vector_type(4))) float f32x4;

__device__ __forceinline__ void gload16(const void* g, void* l) {
  __builtin_amdgcn_global_load_lds(
      (const __attribute__((address_space(1))) void*)g,
      (__attribute__((address_space(3))) void*)l, 16, 0, 0);
}

__device__ __forceinline__ unsigned short f2bf(float f) {
  __hip_bfloat16 h = __float2bfloat16(f);
  return __builtin_bit_cast(unsigned short, h);
}
__device__ __forceinline__ float bf2f(unsigned short u) {
  unsigned int x = ((unsigned int)u) << 16;
  return __builtin_bit_cast(float, x);
}
__device__ __forceinline__ float ex2(float x) {
  float r;
  asm("v_exp_f32 %0, %1" : "=v"(r) : "v"(x));
  return r;
}
__device__ __forceinline__ float frcp(float x) {
  float r;
  asm("v_rcp_f32 %0, %1" : "=v"(r) : "v"(x));
  return r;
}

// ---------------- merged weight fp32 -> bf16 transpose ----------------
__global__ __launch_bounds__(256) void wconv_all(
    const float* __restrict__ qkv_w, const float* __restrict__ proj_w,
    const float* __restrict__ fc1_w, const float* __restrict__ fc2_w,
    unsigned short* __restrict__ wt_qkv, unsigned short* __restrict__ wt_proj,
    unsigned short* __restrict__ wt_fc1, unsigned short* __restrict__ wt_fc2) {
  __shared__ float tile[32][33];
  const int bid = blockIdx.x;
  const float* W;
  unsigned short* Wt;
  int K, Nn, bx, by;
  if (bid < 1728) {
    W = qkv_w; Wt = wt_qkv; K = 768; Nn = 2304;
    bx = bid % 72; by = bid / 72;
  } else if (bid < 1728 + 576) {
    const int i = bid - 1728;
    W = proj_w; Wt = wt_proj; K = 768; Nn = 768;
    bx = i % 24; by = i / 24;
  } else if (bid < 1728 + 576 + 2304) {
    const int i = bid - (1728 + 576);
    W = fc1_w; Wt = wt_fc1; K = 768; Nn = 3072;
    bx = i % 96; by = i / 96;
  } else {
    const int i = bid - (1728 + 576 + 2304);
    W = fc2_w; Wt = wt_fc2; K = 3072; Nn = 768;
    bx = i % 24; by = i / 24;
  }
  const int tx = threadIdx.x & 31, ty = threadIdx.x >> 5;  // 32 x 8
  const int n0 = bx * 32, k0 = by * 32;
#pragma unroll
  for (int i = 0; i < 32; i += 8)
    tile[ty + i][tx] = W[(size_t)(k0 + ty + i) * Nn + n0 + tx];
  __syncthreads();
#pragma unroll
  for (int i = 0; i < 32; i += 8)
    Wt[(size_t)(n0 + ty + i) * K + k0 + tx] = f2bf(tile[tx][ty + i]);
}

// ---------------- LayerNorm (fp32 in -> bf16 out) ----------------
__global__ __launch_bounds__(256) void ln_kernel(const float* __restrict__ x,
                                                 const float* __restrict__ w,
                                                 const float* __restrict__ b,
                                                 unsigned short* __restrict__ out) {
  __shared__ float sbuf[8];
  const int row = blockIdx.x;
  const int t = threadIdx.x;
  const float* xr = x + (size_t)row * C_;
  float v0 = xr[t], v1 = xr[t + 256], v2 = xr[t + 512];
  float s = v0 + v1 + v2;
  float ss = v0 * v0 + v1 * v1 + v2 * v2;
#pragma unroll
  for (int m = 32; m >= 1; m >>= 1) {
    s += __shfl_xor(s, m);
    ss += __shfl_xor(ss, m);
  }
  const int wave = t >> 6, lane = t & 63;
  if (lane == 0) { sbuf[wave] = s; sbuf[4 + wave] = ss; }
  __syncthreads();
  s = sbuf[0] + sbuf[1] + sbuf[2] + sbuf[3];
  ss = sbuf[4] + sbuf[5] + sbuf[6] + sbuf[7];
  const float mu = s * (1.f / C_);
  const float var = ss * (1.f / C_) - mu * mu;
  const float rstd = rsqrtf(var + 1e-6f);
  unsigned short* o = out + (size_t)row * C_;
  o[t]       = f2bf((v0 - mu) * rstd * w[t]       + b[t]);
  o[t + 256] = f2bf((v1 - mu) * rstd * w[t + 256] + b[t + 256]);
  o[t + 512] = f2bf((v2 - mu) * rstd * w[t + 512] + b[t + 512]);
}

// ---------------- GEMM: C = A[M,K] * Bt[N,K]^T + bias, fused epilogue ----------
// BM = MF*32 (MF=4 -> 128, MF=2 -> 64), BN=128, BK=32, 4 waves.
// Depth-4 prefetch, 5 LDS buffers, counted vmcnt, raw s_barrier, setprio.
template <int MF, bool GELU, bool RES, bool OUTF, bool OUTB>
__global__ __launch_bounds__(256) void gemm_bt(const unsigned short* __restrict__ A,
                                               const unsigned short* __restrict__ Bt,
                                               const float* __restrict__ bias,
                                               const float* __restrict__ res,
                                               float* __restrict__ outF,
                                               unsigned short* __restrict__ outB,
                                               int M, int Nn, int K) {
  __shared__ unsigned short As[5][MF * 32 * 32];
  __shared__ unsigned short Bs[5][128 * 32];
  const int t = threadIdx.x;
  const int lane = t & 63;
  const int wave = t >> 6;
  const int wm = wave >> 1, wn = wave & 1;
  const int r15 = lane & 15, g = lane >> 4;

  constexpr int SPX = (MF == 4) ? 4 : 8;
  constexpr int LGS = (MF == 4) ? 2 : 3;
  const int orig = blockIdx.y * gridDim.x + blockIdx.x;
  const int xcd = orig & 7;
  const int j = orig >> 3;
  const int bm = xcd * SPX + (j & (SPX - 1));
  const int bn = j >> LGS;

  f32x4 acc[MF][4];
#pragma unroll
  for (int m = 0; m < MF; ++m)
#pragma unroll
    for (int n = 0; n < 4; ++n) acc[m][n] = (f32x4){0.f, 0.f, 0.f, 0.f};

  const unsigned short* ga0 = A + (size_t)(bm * (MF * 32) + (t >> 2)) * K + (t & 3) * 8;
  const unsigned short* gb0 = Bt + (size_t)(bn * 128 + (t >> 2)) * K + (t & 3) * 8;

#define GSTAGE(kt_, buf_)                                                  \
  {                                                                        \
    const unsigned short* ga = ga0 + (kt_)*32;                             \
    const unsigned short* gb = gb0 + (kt_)*32;                             \
    gload16(ga, (char*)As[buf_] + wave * 1024);                            \
    if constexpr (MF == 4)                                                 \
      gload16(ga + (size_t)64 * K, (char*)As[buf_] + wave * 1024 + 4096);  \
    gload16(gb, (char*)Bs[buf_] + wave * 1024);                            \
    gload16(gb + (size_t)64 * K, (char*)Bs[buf_] + wave * 1024 + 4096);    \
  }

  const int nk = K >> 5;  // >= 24 for all our shapes
  GSTAGE(0, 0);
  GSTAGE(1, 1);
  GSTAGE(2, 2);
  GSTAGE(3, 3);

  int rd = 0;
  for (int kt = 0; kt < nk; ++kt) {
    const int rem = nk - kt;
    if (rem >= 4) {
      if constexpr (MF == 4) asm volatile("s_waitcnt vmcnt(12)" ::: "memory");
      else                   asm volatile("s_waitcnt vmcnt(9)" ::: "memory");
    } else if (rem == 3) {
      if constexpr (MF == 4) asm volatile("s_waitcnt vmcnt(8)" ::: "memory");
      else                   asm volatile("s_waitcnt vmcnt(6)" ::: "memory");
    } else if (rem == 2) {
      if constexpr (MF == 4) asm volatile("s_waitcnt vmcnt(4)" ::: "memory");
      else                   asm volatile("s_waitcnt vmcnt(3)" ::: "memory");
    } else {
      asm volatile("s_waitcnt vmcnt(0)" ::: "memory");
    }
    __builtin_amdgcn_s_barrier();

    short8 af[MF], bf[4];
#pragma unroll
    for (int m = 0; m < MF; ++m)
      af[m] = *(const short8*)(As[rd] + (wm * (MF * 16) + m * 16 + r15) * 32 + g * 8);
#pragma unroll
    for (int n = 0; n < 4; ++n)
      bf[n] = *(const short8*)(Bs[rd] + (wn * 64 + n * 16 + r15) * 32 + g * 8);

    if (kt + 4 < nk) {
      const int wr = (rd == 0) ? 4 : rd - 1;  // == (kt+4)%5
      GSTAGE(kt + 4, wr);
    }

    asm volatile("s_waitcnt lgkmcnt(0)" ::: "memory");
    __builtin_amdgcn_sched_barrier(0);
    __builtin_amdgcn_s_setprio(1);
#pragma unroll
    for (int m = 0; m < MF; ++m)
#pragma unroll
      for (int n = 0; n < 4; ++n)
        acc[m][n] = __builtin_amdgcn_mfma_f32_16x16x32_bf16(af[m], bf[n], acc[m][n], 0, 0, 0);
    __builtin_amdgcn_s_setprio(0);
    rd = (rd == 4) ? 0 : rd + 1;
  }
#undef GSTAGE

#pragma unroll
  for (int m = 0; m < MF; ++m) {
#pragma unroll
    for (int n = 0; n < 4; ++n) {
#pragma unroll
      for (int r = 0; r < 4; ++r) {
        const int row = bm * (MF * 32) + wm * (MF * 16) + m * 16 + g * 4 + r;
        const int col = bn * 128 + wn * 64 + n * 16 + r15;
        float v = acc[m][n][r] + bias[col];
        if (GELU) v = 0.5f * v * (1.f + erff(v * 0.70710678118654752f));
        if (RES) v += res[(size_t)row * Nn + col];
        if (OUTF) outF[(size_t)row * Nn + col] = v;
        if (OUTB) outB[(size_t)row * Nn + col] = f2bf(v);
      }
    }
  }
}

// ---------------- fused biased attention (VALU-diet) ----------------
// Swizzled LDS (conflict-free), K double-buffered via global_load_lds,
// V single-buffer (reg-staged, written at top barrier), per-wave P in LDS.
// Softmax denominator via ones-MFMA (l accumulated in matrix pipe, rescaled
// like O). Bias via 4 running row-pointers with imm offsets.
// grid: (N/64, B*H) = 768 blocks; block: 256 (4 waves x 16 q-rows).
__global__ __launch_bounds__(256) void attn_kernel(const unsigned short* __restrict__ qkv,
                                                   const float* __restrict__ pbias,
                                                   unsigned short* __restrict__ o) {
  __shared__ unsigned short Ks[2][64 * 64];
  __shared__ unsigned short Vt[64 * 64];
  __shared__ unsigned short Ps[4][16 * 64];
  const int t = threadIdx.x, lane = t & 63, wave = t >> 6;
  const int bh = blockIdx.y;
  const int b = bh / H_, h = bh % H_;
  const int q0 = blockIdx.x * 64;
  const int r15 = lane & 15, g = lane >> 4;
  const int qrow = q0 + wave * 16;
  const float LOG2E = 1.44269504088896f;
  const float QS = 0.125f * 1.44269504088896f;  // SCALE * log2(e)
  const int NT = N_ / 64;

  short8 aq[2];
  {
    const unsigned short* qp =
        qkv + (size_t)(b * N_ + qrow + r15) * (3 * C_) + h * D_ + g * 8;
    const ushort8 r0 = *(const ushort8*)qp;
    const ushort8 r1 = *(const ushort8*)(qp + 32);
#pragma unroll
    for (int jj = 0; jj < 8; ++jj) {
      aq[0][jj] = (short)f2bf(bf2f(r0[jj]) * QS);
      aq[1][jj] = (short)f2bf(bf2f(r1[jj]) * QS);
    }
  }
  // ones B-operand for the l-MFMA (bf16 1.0 = 0x3F80)
  short8 ones;
#pragma unroll
  for (int jj = 0; jj < 8; ++jj) ones[jj] = (short)0x3F80;

  f32x4 oacc[4], lacc;
#pragma unroll
  for (int n = 0; n < 4; ++n) oacc[n] = (f32x4){0.f, 0.f, 0.f, 0.f};
  lacc = (f32x4){0.f, 0.f, 0.f, 0.f};
  float m_run[4];
#pragma unroll
  for (int r = 0; r < 4; ++r) m_run[r] = -1e30f;

  const unsigned short* kbase = qkv + (size_t)b * N_ * (3 * C_) + C_ + h * D_;
  const unsigned short* vbase = qkv + (size_t)b * N_ * (3 * C_) + 2 * C_ + h * D_;

  // bias running row pointers (one per r), advanced 64 floats per tile
  const float* bp[4];
#pragma unroll
  for (int r = 0; r < 4; ++r)
    bp[r] = pbias + (size_t)b * N_ * N_ + (size_t)(qrow + g * 4 + r) * N_ + r15;

  const int krow = t >> 3;
  const int kchunk = (t & 7) ^ (krow & 7);
  const int vp = t & 31;
  const int vq = t >> 5;
  const int vkey = vp * 2, vd0 = vq * 8;

#define KSTAGE(kb_, nb_)                                                       \
  {                                                                            \
    const unsigned short* kg =                                                 \
        kbase + (size_t)((kb_)*64 + krow) * (3 * C_) + kchunk * 8;             \
    gload16(kg, (char*)Ks[nb_] + wave * 1024);                                 \
    gload16(kg + (size_t)32 * (3 * C_), (char*)Ks[nb_] + wave * 1024 + 4096);  \
  }

#define VWRITE(va_, vb_)                                                             \
  {                                                                                  \
    char* vdst = (char*)Vt;                                                          \
    _Pragma("unroll") for (int jj = 0; jj < 8; ++jj) {                               \
      const int d = vd0 + jj;                                                        \
      const unsigned int pack =                                                      \
          (unsigned int)(va_)[jj] | ((unsigned int)(vb_)[jj] << 16);                 \
      *(unsigned int*)(vdst + d * 128 + (((vp >> 2) ^ (d & 7)) << 4) +               \
                       (vp & 3) * 4) = pack;                                         \
    }                                                                                \
  }

  // Prologue: K(0) -> LDS (async), V(0)/bias(0) -> regs.
  KSTAGE(0, 0);
  ushort8 va, vb2;
  {
    const unsigned short* vg = vbase + (size_t)vkey * (3 * C_) + vd0;
    va = *(const ushort8*)vg;
    vb2 = *(const ushort8*)(vg + 3 * C_);
  }
  float bcur[4][4], bnext[4][4];
#pragma unroll
  for (int n = 0; n < 4; ++n)
#pragma unroll
    for (int r = 0; r < 4; ++r) bcur[n][r] = bp[r][n * 16];

  for (int kb = 0; kb < NT; ++kb) {
    const int cur = kb & 1;
    __syncthreads();  // K[kb] staged & visible; all waves' PV[kb-1] complete

    VWRITE(va, vb2);  // Vt <- V tile kb

    const bool more = (kb + 1 < NT);
    if (more) {
      KSTAGE(kb + 1, cur ^ 1);
      const unsigned short* vg =
          vbase + (size_t)((kb + 1) * 64 + vkey) * (3 * C_) + vd0;
      va = *(const ushort8*)vg;
      vb2 = *(const ushort8*)(vg + 3 * C_);
#pragma unroll
      for (int n = 0; n < 4; ++n)
#pragma unroll
        for (int r = 0; r < 4; ++r) bnext[n][r] = bp[r][64 + n * 16];
    }
#pragma unroll
    for (int r = 0; r < 4; ++r) bp[r] += 64;

    // S = Q K^T (16 x 64 per wave), log2-scaled domain
    const unsigned short* Ksc = Ks[cur];
    f32x4 sacc[4];
#pragma unroll
    for (int n = 0; n < 4; ++n) sacc[n] = (f32x4){0.f, 0.f, 0.f, 0.f};
    __builtin_amdgcn_s_setprio(1);
#pragma unroll
    for (int kk = 0; kk < 2; ++kk) {
#pragma unroll
      for (int n = 0; n < 4; ++n) {
        short8 bk = *(const short8*)(Ksc + (n * 16 + r15) * 64 +
                                     (((kk * 4 + g) ^ (r15 & 7)) << 3));
        sacc[n] = __builtin_amdgcn_mfma_f32_16x16x32_bf16(aq[kk], bk, sacc[n], 0, 0, 0);
      }
    }
    __builtin_amdgcn_s_setprio(0);

    // online softmax (log2 domain, defer-max, sum via ones-MFMA)
    float p[4][4], tm[4];
#pragma unroll
    for (int n = 0; n < 4; ++n)
#pragma unroll
      for (int r = 0; r < 4; ++r)
        p[n][r] = fmaf(bcur[n][r], LOG2E, sacc[n][r]);
#pragma unroll
    for (int r = 0; r < 4; ++r)
      tm[r] = fmaxf(fmaxf(p[0][r], p[1][r]), fmaxf(p[2][r], p[3][r]));
#pragma unroll
    for (int r = 0; r < 4; ++r) {
      tm[r] = fmaxf(tm[r], __shfl_xor(tm[r], 1));
      tm[r] = fmaxf(tm[r], __shfl_xor(tm[r], 2));
      tm[r] = fmaxf(tm[r], __shfl_xor(tm[r], 4));
      tm[r] = fmaxf(tm[r], __shfl_xor(tm[r], 8));
    }
    int need = 0;
#pragma unroll
    for (int r = 0; r < 4; ++r) need |= (tm[r] > m_run[r] + 8.0f);
    if (__any(need)) {
#pragma unroll
      for (int r = 0; r < 4; ++r) {
        const float mn = fmaxf(m_run[r], tm[r]);
        const float corr = ex2(m_run[r] - mn);
        m_run[r] = mn;
        lacc[r] *= corr;
#pragma unroll
        for (int n = 0; n < 4; ++n) oacc[n][r] *= corr;
      }
    }
#pragma unroll
    for (int n = 0; n < 4; ++n)
#pragma unroll
      for (int r = 0; r < 4; ++r) p[n][r] = ex2(p[n][r] - m_run[r]);

    // P -> per-wave LDS (swizzled)
    unsigned short* Psw = Ps[wave];
#pragma unroll
    for (int n = 0; n < 4; ++n)
#pragma unroll
      for (int r = 0; r < 4; ++r) {
        const int row = g * 4 + r, col = n * 16 + r15;
        Psw[row * 64 + (((col >> 3) ^ (row & 7)) << 3) + (col & 7)] = f2bf(p[n][r]);
      }

    // lgkm-only barrier: VWRITE + own Ps visible; global prefetch in flight.
    asm volatile("s_waitcnt lgkmcnt(0)" ::: "memory");
    __builtin_amdgcn_s_barrier();
    __builtin_amdgcn_sched_barrier(0);

    // O += P V ; l += P * 1 (ones-MFMA)
    __builtin_amdgcn_s_setprio(1);
#pragma unroll
    for (int kk = 0; kk < 2; ++kk) {
      short8 ap = *(const short8*)(Psw + r15 * 64 + (((kk * 4 + g) ^ (r15 & 7)) << 3));
      lacc = __builtin_amdgcn_mfma_f32_16x16x32_bf16(ap, ones, lacc, 0, 0, 0);
#pragma unroll
      for (int n = 0; n < 4; ++n) {
        short8 bv = *(const short8*)(Vt + (n * 16 + r15) * 64 +
                                     (((kk * 4 + g) ^ (r15 & 7)) << 3));
        oacc[n] = __builtin_amdgcn_mfma_f32_16x16x32_bf16(ap, bv, oacc[n], 0, 0, 0);
      }
    }
    __builtin_amdgcn_s_setprio(0);

    if (more) {
#pragma unroll
      for (int n = 0; n < 4; ++n)
#pragma unroll
        for (int r = 0; r < 4; ++r) bcur[n][r] = bnext[n][r];
    }
  }
#undef KSTAGE
#undef VWRITE

  // normalize and store o (bf16)
  float rl[4];
#pragma unroll
  for (int r = 0; r < 4; ++r) rl[r] = frcp(lacc[r]);
#pragma unroll
  for (int n = 0; n < 4; ++n) {
#pragma unroll
    for (int r = 0; r < 4; ++r) {
      const int row = qrow + g * 4 + r;
      const float v = oacc[n][r] * rl[r];
      o[(size_t)(b * N_ + row) * C_ + h * D_ + n * 16 + r15] = f2bf(v);
    }
  }
}

// ---------------- launcher ----------------
extern "C" void kernel_launch(void* const* d_in, const int* in_sizes, int n_in,
                              void* d_out, int out_size, void* d_ws, size_t ws_size,
                              hipStream_t stream) {
  const float* x      = (const float*)d_in[0];
  const float* pbias  = (const float*)d_in[1];
  const float* qkv_w  = (const float*)d_in[2];
  const float* qkv_b  = (const float*)d_in[3];
  const float* proj_w = (const float*)d_in[4];
  const float* proj_b = (const float*)d_in[5];
  const float* n1_w   = (const float*)d_in[6];
  const float* n1_b   = (const float*)d_in[7];
  const float* n2_w   = (const float*)d_in[8];
  const float* n2_b   = (const float*)d_in[9];
  const float* fc1_w  = (const float*)d_in[10];
  const float* fc1_b  = (const float*)d_in[11];
  const float* fc2_w  = (const float*)d_in[12];
  const float* fc2_b  = (const float*)d_in[13];
  float* out = (float*)d_out;

  char* ws = (char*)d_ws;
  unsigned short* wt_qkv  = (unsigned short*)(ws + 0);          // 2304x768 bf16
  unsigned short* wt_proj = (unsigned short*)(ws + 3538944);    // 768x768
  unsigned short* wt_fc1  = (unsigned short*)(ws + 4718592);    // 3072x768
  unsigned short* wt_fc2  = (unsigned short*)(ws + 9437184);    // 768x3072
  float*          x2      = (float*)(ws + 14155776);            // 4096x768 fp32
  unsigned short* h1      = (unsigned short*)(ws + 26738688);   // 4096x768 bf16
  unsigned short* qkvb    = (unsigned short*)(ws + 33030144);   // 4096x2304 bf16

  wconv_all<<<1728 + 576 + 2304 + 2304, 256, 0, stream>>>(
      qkv_w, proj_w, fc1_w, fc2_w, wt_qkv, wt_proj, wt_fc1, wt_fc2);

  ln_kernel<<<M_, 256, 0, stream>>>(x, n1_w, n1_b, h1);
  gemm_bt<4, false, false, false, true><<<dim3(32, 18), 256, 0, stream>>>(
      h1, wt_qkv, qkv_b, nullptr, nullptr, qkvb, M_, 3 * C_, C_);
  attn_kernel<<<dim3(N_ / 64, B_ * H_), 256, 0, stream>>>(qkvb, pbias, h1);
  gemm_bt<2, false, true, true, false><<<dim3(64, 6), 256, 0, stream>>>(
      h1, wt_proj, proj_b, x, x2, nullptr, M_, C_, C_);
  ln_kernel<<<M_, 256, 0, stream>>>(x2, n2_w, n2_b, h1);
  gemm_bt<4, true, false, false, true><<<dim3(32, 24), 256, 0, stream>>>(
      h1, wt_fc1, fc1_b, nullptr, nullptr, qkvb, M_, HID_, C_);
  gemm_bt<2, false, true, true, false><<<dim3(64, 6), 256, 0, stream>>>(
      qkvb, wt_fc2, fc2_b, x2, out, nullptr, M_, C_, HID_);
}

// Round 8
// 178.222 us; speedup vs baseline: 1.2356x; 1.1169x over previous
//
#include <hip/hip_runtime.h>
#include <hip/hip_bf16.h>
#include <cstdint>
#include <cstddef>

// Problem dims (fixed)
#define B_   4
#define N_   1024
#define C_   768
#define H_   12
#define D_   64
#define HID_ 3072
#define M_   4096  // B*N

typedef __attribute__((ext_vector_type(8))) short short8;
typedef __attribute__((ext_vector_type(8))) unsigned short ushort8;
typedef __attribute__((ext_vector_type(4))) float f32x4;

__device__ __forceinline__ void gload16(const void* g, void* l) {
  __builtin_amdgcn_global_load_lds(
      (const __attribute__((address_space(1))) void*)g,
      (__attribute__((address_space(3))) void*)l, 16, 0, 0);
}

__device__ __forceinline__ unsigned short f2bf(float f) {
  __hip_bfloat16 h = __float2bfloat16(f);
  return __builtin_bit_cast(unsigned short, h);
}
__device__ __forceinline__ float bf2f(unsigned short u) {
  unsigned int x = ((unsigned int)u) << 16;
  return __builtin_bit_cast(float, x);
}
__device__ __forceinline__ float ex2(float x) {
  float r;
  asm("v_exp_f32 %0, %1" : "=v"(r) : "v"(x));
  return r;
}
__device__ __forceinline__ float frcp(float x) {
  float r;
  asm("v_rcp_f32 %0, %1" : "=v"(r) : "v"(x));
  return r;
}

// ---------------- merged weight fp32 -> bf16 transpose ----------------
__global__ __launch_bounds__(256) void wconv_all(
    const float* __restrict__ qkv_w, const float* __restrict__ proj_w,
    const float* __restrict__ fc1_w, const float* __restrict__ fc2_w,
    unsigned short* __restrict__ wt_qkv, unsigned short* __restrict__ wt_proj,
    unsigned short* __restrict__ wt_fc1, unsigned short* __restrict__ wt_fc2) {
  __shared__ float tile[32][33];
  const int bid = blockIdx.x;
  const float* W;
  unsigned short* Wt;
  int K, Nn, bx, by;
  if (bid < 1728) {
    W = qkv_w; Wt = wt_qkv; K = 768; Nn = 2304;
    bx = bid % 72; by = bid / 72;
  } else if (bid < 1728 + 576) {
    const int i = bid - 1728;
    W = proj_w; Wt = wt_proj; K = 768; Nn = 768;
    bx = i % 24; by = i / 24;
  } else if (bid < 1728 + 576 + 2304) {
    const int i = bid - (1728 + 576);
    W = fc1_w; Wt = wt_fc1; K = 768; Nn = 3072;
    bx = i % 96; by = i / 96;
  } else {
    const int i = bid - (1728 + 576 + 2304);
    W = fc2_w; Wt = wt_fc2; K = 3072; Nn = 768;
    bx = i % 24; by = i / 24;
  }
  const int tx = threadIdx.x & 31, ty = threadIdx.x >> 5;  // 32 x 8
  const int n0 = bx * 32, k0 = by * 32;
#pragma unroll
  for (int i = 0; i < 32; i += 8)
    tile[ty + i][tx] = W[(size_t)(k0 + ty + i) * Nn + n0 + tx];
  __syncthreads();
#pragma unroll
  for (int i = 0; i < 32; i += 8)
    Wt[(size_t)(n0 + ty + i) * K + k0 + tx] = f2bf(tile[tx][ty + i]);
}

// ---------------- LayerNorm (fp32 in -> bf16 out) ----------------
__global__ __launch_bounds__(256) void ln_kernel(const float* __restrict__ x,
                                                 const float* __restrict__ w,
                                                 const float* __restrict__ b,
                                                 unsigned short* __restrict__ out) {
  __shared__ float sbuf[8];
  const int row = blockIdx.x;
  const int t = threadIdx.x;
  const float* xr = x + (size_t)row * C_;
  float v0 = xr[t], v1 = xr[t + 256], v2 = xr[t + 512];
  float s = v0 + v1 + v2;
  float ss = v0 * v0 + v1 * v1 + v2 * v2;
#pragma unroll
  for (int m = 32; m >= 1; m >>= 1) {
    s += __shfl_xor(s, m);
    ss += __shfl_xor(ss, m);
  }
  const int wave = t >> 6, lane = t & 63;
  if (lane == 0) { sbuf[wave] = s; sbuf[4 + wave] = ss; }
  __syncthreads();
  s = sbuf[0] + sbuf[1] + sbuf[2] + sbuf[3];
  ss = sbuf[4] + sbuf[5] + sbuf[6] + sbuf[7];
  const float mu = s * (1.f / C_);
  const float var = ss * (1.f / C_) - mu * mu;
  const float rstd = rsqrtf(var + 1e-6f);
  unsigned short* o = out + (size_t)row * C_;
  o[t]       = f2bf((v0 - mu) * rstd * w[t]       + b[t]);
  o[t + 256] = f2bf((v1 - mu) * rstd * w[t + 256] + b[t + 256]);
  o[t + 512] = f2bf((v2 - mu) * rstd * w[t + 512] + b[t + 512]);
}

// ---------------- GEMM: C = A[M,K] * Bt[N,K]^T + bias, fused epilogue ----------
// BM = MF*32 (MF=4 -> 128, MF=2 -> 64), BN=128, BK=32, 4 waves.
// 3 LDS buffers (48KB MF4 / 36KB MF2 -> 3-4 blocks/CU, grids fully resident),
// depth-2 prefetch with counted vmcnt, raw s_barrier, setprio around MFMA.
// LDS chunk XOR-swizzle (2-way optimal): src chunk (t&3)^((t>>3)&3),
// read slot g^((row>>1)&3) -- spreads each b128 quarter-wave over 8 bank-quads.
template <int MF, bool GELU, bool RES, bool OUTF, bool OUTB>
__global__ __launch_bounds__(256) void gemm_bt(const unsigned short* __restrict__ A,
                                               const unsigned short* __restrict__ Bt,
                                               const float* __restrict__ bias,
                                               const float* __restrict__ res,
                                               float* __restrict__ outF,
                                               unsigned short* __restrict__ outB,
                                               int M, int Nn, int K) {
  __shared__ unsigned short As[3][MF * 32 * 32];
  __shared__ unsigned short Bs[3][128 * 32];
  const int t = threadIdx.x;
  const int lane = t & 63;
  const int wave = t >> 6;
  const int wm = wave >> 1, wn = wave & 1;
  const int r15 = lane & 15, g = lane >> 4;

  constexpr int SPX = (MF == 4) ? 4 : 8;
  constexpr int LGS = (MF == 4) ? 2 : 3;
  const int orig = blockIdx.y * gridDim.x + blockIdx.x;
  const int xcd = orig & 7;
  const int j = orig >> 3;
  const int bm = xcd * SPX + (j & (SPX - 1));
  const int bn = j >> LGS;

  f32x4 acc[MF][4];
#pragma unroll
  for (int m = 0; m < MF; ++m)
#pragma unroll
    for (int n = 0; n < 4; ++n) acc[m][n] = (f32x4){0.f, 0.f, 0.f, 0.f};

  // pre-swizzled source chunk so linear gload_lds dest = swizzled layout
  const int srow = t >> 2;                       // 0..63 (row within half-tile)
  const int schunk = (t & 3) ^ ((t >> 3) & 3);   // xor (srow>>1)&3
  const unsigned short* ga0 = A + (size_t)(bm * (MF * 32) + srow) * K + schunk * 8;
  const unsigned short* gb0 = Bt + (size_t)(bn * 128 + srow) * K + schunk * 8;

#define GSTAGE(kt_, buf_)                                                  \
  {                                                                        \
    const unsigned short* ga = ga0 + (kt_)*32;                             \
    const unsigned short* gb = gb0 + (kt_)*32;                             \
    gload16(ga, (char*)As[buf_] + wave * 1024);                            \
    if constexpr (MF == 4)                                                 \
      gload16(ga + (size_t)64 * K, (char*)As[buf_] + wave * 1024 + 4096);  \
    gload16(gb, (char*)Bs[buf_] + wave * 1024);                            \
    gload16(gb + (size_t)64 * K, (char*)Bs[buf_] + wave * 1024 + 4096);    \
  }

  const int nk = K >> 5;  // >= 24 for all our shapes
  GSTAGE(0, 0);
  GSTAGE(1, 1);

  // read slots (LDS shorts offset = row*32 + slot*8)
  int arow[MF], aoff[MF], boff[4];
#pragma unroll
  for (int m = 0; m < MF; ++m) {
    arow[m] = wm * (MF * 16) + m * 16 + r15;
    aoff[m] = arow[m] * 32 + (g ^ ((arow[m] >> 1) & 3)) * 8;
  }
#pragma unroll
  for (int n = 0; n < 4; ++n) {
    const int rn = wn * 64 + n * 16 + r15;
    boff[n] = rn * 32 + (g ^ ((rn >> 1) & 3)) * 8;
  }

  int rd = 0;
  for (int kt = 0; kt < nk; ++kt) {
    const int rem = nk - kt;
    if (rem >= 2) {
      if constexpr (MF == 4) asm volatile("s_waitcnt vmcnt(4)" ::: "memory");
      else                   asm volatile("s_waitcnt vmcnt(3)" ::: "memory");
    } else {
      asm volatile("s_waitcnt vmcnt(0)" ::: "memory");
    }
    __builtin_amdgcn_s_barrier();

    short8 af[MF], bf[4];
#pragma unroll
    for (int m = 0; m < MF; ++m)
      af[m] = *(const short8*)(As[rd] + aoff[m]);
#pragma unroll
    for (int n = 0; n < 4; ++n)
      bf[n] = *(const short8*)(Bs[rd] + boff[n]);

    if (kt + 2 < nk) {
      const int wr = (rd + 2 >= 3) ? rd - 1 : rd + 2;  // (kt+2)%3
      GSTAGE(kt + 2, wr);
    }

    asm volatile("s_waitcnt lgkmcnt(0)" ::: "memory");
    __builtin_amdgcn_sched_barrier(0);
    __builtin_amdgcn_s_setprio(1);
#pragma unroll
    for (int m = 0; m < MF; ++m)
#pragma unroll
      for (int n = 0; n < 4; ++n)
        acc[m][n] = __builtin_amdgcn_mfma_f32_16x16x32_bf16(af[m], bf[n], acc[m][n], 0, 0, 0);
    __builtin_amdgcn_s_setprio(0);
    rd = (rd == 2) ? 0 : rd + 1;
  }
#undef GSTAGE

#pragma unroll
  for (int m = 0; m < MF; ++m) {
#pragma unroll
    for (int n = 0; n < 4; ++n) {
#pragma unroll
      for (int r = 0; r < 4; ++r) {
        const int row = bm * (MF * 32) + wm * (MF * 16) + m * 16 + g * 4 + r;
        const int col = bn * 128 + wn * 64 + n * 16 + r15;
        float v = acc[m][n][r] + bias[col];
        if (GELU) v = 0.5f * v * (1.f + erff(v * 0.70710678118654752f));
        if (RES) v += res[(size_t)row * Nn + col];
        if (OUTF) outF[(size_t)row * Nn + col] = v;
        if (OUTB) outB[(size_t)row * Nn + col] = f2bf(v);
      }
    }
  }
}

// ---------------- fused biased attention (VALU-diet) ----------------
// Swizzled LDS (conflict-free), K double-buffered via global_load_lds,
// V single-buffer (reg-staged, written at top barrier), per-wave P in LDS.
// Softmax denominator via ones-MFMA. Bias via running row-pointers.
// grid: (N/64, B*H) = 768 blocks; block: 256 (4 waves x 16 q-rows).
__global__ __launch_bounds__(256) void attn_kernel(const unsigned short* __restrict__ qkv,
                                                   const float* __restrict__ pbias,
                                                   unsigned short* __restrict__ o) {
  __shared__ unsigned short Ks[2][64 * 64];
  __shared__ unsigned short Vt[64 * 64];
  __shared__ unsigned short Ps[4][16 * 64];
  const int t = threadIdx.x, lane = t & 63, wave = t >> 6;
  const int bh = blockIdx.y;
  const int b = bh / H_, h = bh % H_;
  const int q0 = blockIdx.x * 64;
  const int r15 = lane & 15, g = lane >> 4;
  const int qrow = q0 + wave * 16;
  const float LOG2E = 1.44269504088896f;
  const float QS = 0.125f * 1.44269504088896f;  // SCALE * log2(e)
  const int NT = N_ / 64;

  short8 aq[2];
  {
    const unsigned short* qp =
        qkv + (size_t)(b * N_ + qrow + r15) * (3 * C_) + h * D_ + g * 8;
    const ushort8 r0 = *(const ushort8*)qp;
    const ushort8 r1 = *(const ushort8*)(qp + 32);
#pragma unroll
    for (int jj = 0; jj < 8; ++jj) {
      aq[0][jj] = (short)f2bf(bf2f(r0[jj]) * QS);
      aq[1][jj] = (short)f2bf(bf2f(r1[jj]) * QS);
    }
  }
  short8 ones;
#pragma unroll
  for (int jj = 0; jj < 8; ++jj) ones[jj] = (short)0x3F80;

  f32x4 oacc[4], lacc;
#pragma unroll
  for (int n = 0; n < 4; ++n) oacc[n] = (f32x4){0.f, 0.f, 0.f, 0.f};
  lacc = (f32x4){0.f, 0.f, 0.f, 0.f};
  float m_run[4];
#pragma unroll
  for (int r = 0; r < 4; ++r) m_run[r] = -1e30f;

  const unsigned short* kbase = qkv + (size_t)b * N_ * (3 * C_) + C_ + h * D_;
  const unsigned short* vbase = qkv + (size_t)b * N_ * (3 * C_) + 2 * C_ + h * D_;

  const float* bp[4];
#pragma unroll
  for (int r = 0; r < 4; ++r)
    bp[r] = pbias + (size_t)b * N_ * N_ + (size_t)(qrow + g * 4 + r) * N_ + r15;

  const int krow = t >> 3;
  const int kchunk = (t & 7) ^ (krow & 7);
  const int vp = t & 31;
  const int vq = t >> 5;
  const int vkey = vp * 2, vd0 = vq * 8;

#define KSTAGE(kb_, nb_)                                                       \
  {                                                                            \
    const unsigned short* kg =                                                 \
        kbase + (size_t)((kb_)*64 + krow) * (3 * C_) + kchunk * 8;             \
    gload16(kg, (char*)Ks[nb_] + wave * 1024);                                 \
    gload16(kg + (size_t)32 * (3 * C_), (char*)Ks[nb_] + wave * 1024 + 4096);  \
  }

#define VWRITE(va_, vb_)                                                             \
  {                                                                                  \
    char* vdst = (char*)Vt;                                                          \
    _Pragma("unroll") for (int jj = 0; jj < 8; ++jj) {                               \
      const int d = vd0 + jj;                                                        \
      const unsigned int pack =                                                      \
          (unsigned int)(va_)[jj] | ((unsigned int)(vb_)[jj] << 16);                 \
      *(unsigned int*)(vdst + d * 128 + (((vp >> 2) ^ (d & 7)) << 4) +               \
                       (vp & 3) * 4) = pack;                                         \
    }                                                                                \
  }

  KSTAGE(0, 0);
  ushort8 va, vb2;
  {
    const unsigned short* vg = vbase + (size_t)vkey * (3 * C_) + vd0;
    va = *(const ushort8*)vg;
    vb2 = *(const ushort8*)(vg + 3 * C_);
  }
  float bcur[4][4], bnext[4][4];
#pragma unroll
  for (int n = 0; n < 4; ++n)
#pragma unroll
    for (int r = 0; r < 4; ++r) bcur[n][r] = bp[r][n * 16];

  for (int kb = 0; kb < NT; ++kb) {
    const int cur = kb & 1;
    __syncthreads();  // K[kb] staged & visible; all waves' PV[kb-1] complete

    VWRITE(va, vb2);

    const bool more = (kb + 1 < NT);
    if (more) {
      KSTAGE(kb + 1, cur ^ 1);
      const unsigned short* vg =
          vbase + (size_t)((kb + 1) * 64 + vkey) * (3 * C_) + vd0;
      va = *(const ushort8*)vg;
      vb2 = *(const ushort8*)(vg + 3 * C_);
#pragma unroll
      for (int n = 0; n < 4; ++n)
#pragma unroll
        for (int r = 0; r < 4; ++r) bnext[n][r] = bp[r][64 + n * 16];
    }
#pragma unroll
    for (int r = 0; r < 4; ++r) bp[r] += 64;

    const unsigned short* Ksc = Ks[cur];
    f32x4 sacc[4];
#pragma unroll
    for (int n = 0; n < 4; ++n) sacc[n] = (f32x4){0.f, 0.f, 0.f, 0.f};
    __builtin_amdgcn_s_setprio(1);
#pragma unroll
    for (int kk = 0; kk < 2; ++kk) {
#pragma unroll
      for (int n = 0; n < 4; ++n) {
        short8 bk = *(const short8*)(Ksc + (n * 16 + r15) * 64 +
                                     (((kk * 4 + g) ^ (r15 & 7)) << 3));
        sacc[n] = __builtin_amdgcn_mfma_f32_16x16x32_bf16(aq[kk], bk, sacc[n], 0, 0, 0);
      }
    }
    __builtin_amdgcn_s_setprio(0);

    float p[4][4], tm[4];
#pragma unroll
    for (int n = 0; n < 4; ++n)
#pragma unroll
      for (int r = 0; r < 4; ++r)
        p[n][r] = fmaf(bcur[n][r], LOG2E, sacc[n][r]);
#pragma unroll
    for (int r = 0; r < 4; ++r)
      tm[r] = fmaxf(fmaxf(p[0][r], p[1][r]), fmaxf(p[2][r], p[3][r]));
#pragma unroll
    for (int r = 0; r < 4; ++r) {
      tm[r] = fmaxf(tm[r], __shfl_xor(tm[r], 1));
      tm[r] = fmaxf(tm[r], __shfl_xor(tm[r], 2));
      tm[r] = fmaxf(tm[r], __shfl_xor(tm[r], 4));
      tm[r] = fmaxf(tm[r], __shfl_xor(tm[r], 8));
    }
    int need = 0;
#pragma unroll
    for (int r = 0; r < 4; ++r) need |= (tm[r] > m_run[r] + 8.0f);
    if (__any(need)) {
#pragma unroll
      for (int r = 0; r < 4; ++r) {
        const float mn = fmaxf(m_run[r], tm[r]);
        const float corr = ex2(m_run[r] - mn);
        m_run[r] = mn;
        lacc[r] *= corr;
#pragma unroll
        for (int n = 0; n < 4; ++n) oacc[n][r] *= corr;
      }
    }
#pragma unroll
    for (int n = 0; n < 4; ++n)
#pragma unroll
      for (int r = 0; r < 4; ++r) p[n][r] = ex2(p[n][r] - m_run[r]);

    unsigned short* Psw = Ps[wave];
#pragma unroll
    for (int n = 0; n < 4; ++n)
#pragma unroll
      for (int r = 0; r < 4; ++r) {
        const int row = g * 4 + r, col = n * 16 + r15;
        Psw[row * 64 + (((col >> 3) ^ (row & 7)) << 3) + (col & 7)] = f2bf(p[n][r]);
      }

    asm volatile("s_waitcnt lgkmcnt(0)" ::: "memory");
    __builtin_amdgcn_s_barrier();
    __builtin_amdgcn_sched_barrier(0);

    __builtin_amdgcn_s_setprio(1);
#pragma unroll
    for (int kk = 0; kk < 2; ++kk) {
      short8 ap = *(const short8*)(Psw + r15 * 64 + (((kk * 4 + g) ^ (r15 & 7)) << 3));
      lacc = __builtin_amdgcn_mfma_f32_16x16x32_bf16(ap, ones, lacc, 0, 0, 0);
#pragma unroll
      for (int n = 0; n < 4; ++n) {
        short8 bv = *(const short8*)(Vt + (n * 16 + r15) * 64 +
                                     (((kk * 4 + g) ^ (r15 & 7)) << 3));
        oacc[n] = __builtin_amdgcn_mfma_f32_16x16x32_bf16(ap, bv, oacc[n], 0, 0, 0);
      }
    }
    __builtin_amdgcn_s_setprio(0);

    if (more) {
#pragma unroll
      for (int n = 0; n < 4; ++n)
#pragma unroll
        for (int r = 0; r < 4; ++r) bcur[n][r] = bnext[n][r];
    }
  }
#undef KSTAGE
#undef VWRITE

  float rl[4];
#pragma unroll
  for (int r = 0; r < 4; ++r) rl[r] = frcp(lacc[r]);
#pragma unroll
  for (int n = 0; n < 4; ++n) {
#pragma unroll
    for (int r = 0; r < 4; ++r) {
      const int row = qrow + g * 4 + r;
      const float v = oacc[n][r] * rl[r];
      o[(size_t)(b * N_ + row) * C_ + h * D_ + n * 16 + r15] = f2bf(v);
    }
  }
}

// ---------------- launcher ----------------
extern "C" void kernel_launch(void* const* d_in, const int* in_sizes, int n_in,
                              void* d_out, int out_size, void* d_ws, size_t ws_size,
                              hipStream_t stream) {
  const float* x      = (const float*)d_in[0];
  const float* pbias  = (const float*)d_in[1];
  const float* qkv_w  = (const float*)d_in[2];
  const float* qkv_b  = (const float*)d_in[3];
  const float* proj_w = (const float*)d_in[4];
  const float* proj_b = (const float*)d_in[5];
  const float* n1_w   = (const float*)d_in[6];
  const float* n1_b   = (const float*)d_in[7];
  const float* n2_w   = (const float*)d_in[8];
  const float* n2_b   = (const float*)d_in[9];
  const float* fc1_w  = (const float*)d_in[10];
  const float* fc1_b  = (const float*)d_in[11];
  const float* fc2_w  = (const float*)d_in[12];
  const float* fc2_b  = (const float*)d_in[13];
  float* out = (float*)d_out;

  char* ws = (char*)d_ws;
  unsigned short* wt_qkv  = (unsigned short*)(ws + 0);          // 2304x768 bf16
  unsigned short* wt_proj = (unsigned short*)(ws + 3538944);    // 768x768
  unsigned short* wt_fc1  = (unsigned short*)(ws + 4718592);    // 3072x768
  unsigned short* wt_fc2  = (unsigned short*)(ws + 9437184);    // 768x3072
  float*          x2      = (float*)(ws + 14155776);            // 4096x768 fp32
  unsigned short* h1      = (unsigned short*)(ws + 26738688);   // 4096x768 bf16
  unsigned short* qkvb    = (unsigned short*)(ws + 33030144);   // 4096x2304 bf16

  wconv_all<<<1728 + 576 + 2304 + 2304, 256, 0, stream>>>(
      qkv_w, proj_w, fc1_w, fc2_w, wt_qkv, wt_proj, wt_fc1, wt_fc2);

  ln_kernel<<<M_, 256, 0, stream>>>(x, n1_w, n1_b, h1);
  gemm_bt<4, false, false, false, true><<<dim3(32, 18), 256, 0, stream>>>(
      h1, wt_qkv, qkv_b, nullptr, nullptr, qkvb, M_, 3 * C_, C_);
  attn_kernel<<<dim3(N_ / 64, B_ * H_), 256, 0, stream>>>(qkvb, pbias, h1);
  gemm_bt<2, false, true, true, false><<<dim3(64, 6), 256, 0, stream>>>(
      h1, wt_proj, proj_b, x, x2, nullptr, M_, C_, C_);
  ln_kernel<<<M_, 256, 0, stream>>>(x2, n2_w, n2_b, h1);
  gemm_bt<4, true, false, false, true><<<dim3(32, 24), 256, 0, stream>>>(
      h1, wt_fc1, fc1_b, nullptr, nullptr, qkvb, M_, HID_, C_);
  gemm_bt<2, false, true, true, false><<<dim3(64, 6), 256, 0, stream>>>(
      qkvb, wt_fc2, fc2_b, x2, out, nullptr, M_, C_, HID_);
}